// Round 4
// baseline (471.999 us; speedup 1.0000x reference)
//
#include <hip/hip_runtime.h>
#include <stdint.h>

#define IN_F 768
#define HID 256
#define OUTF 128

typedef short bf16x8 __attribute__((ext_vector_type(8)));
typedef float f32x4 __attribute__((ext_vector_type(4)));

__device__ inline short f2bf(float f) {
  union { float f; uint32_t u; } x; x.f = f;
  uint32_t r = (x.u + 0x7fffu + ((x.u >> 16) & 1u)) >> 16;  // RNE, finite inputs
  return (short)(uint16_t)r;
}
__device__ inline float bf2f(uint32_t bits) {
  union { uint32_t u; float f; } x; x.u = bits << 16; return x.f;
}

// ---------------- CSR build ----------------
__global__ void k_zero(int* p, int n) {
  int i = blockIdx.x * blockDim.x + threadIdx.x;
  if (i < n) p[i] = 0;
}

__global__ void k_hist(const int* __restrict__ dst, int* __restrict__ cnt, int e) {
  int i = blockIdx.x * blockDim.x + threadIdx.x;
  if (i < e) atomicAdd(&cnt[dst[i]], 1);
}

#define SCAN_B 1024
__global__ void k_bsum(const int* __restrict__ cnt, int* __restrict__ bsum, int n) {
  __shared__ int sm[SCAN_B];
  int t = threadIdx.x;
  int i = blockIdx.x * SCAN_B + t;
  sm[t] = (i < n) ? cnt[i] : 0;
  __syncthreads();
  for (int off = SCAN_B / 2; off > 0; off >>= 1) {
    if (t < off) sm[t] += sm[t + off];
    __syncthreads();
  }
  if (t == 0) bsum[blockIdx.x] = sm[0];
}

// local scan + on-the-fly prefix of bsum -> rowp, cursor, dinv
__global__ void k_scan2(const int* __restrict__ cnt, const int* __restrict__ bsum,
                        int* __restrict__ rowp, int* __restrict__ cursor,
                        float* __restrict__ dinv, int n) {
  __shared__ int sm[SCAN_B];
  __shared__ int boff_s;
  int t = threadIdx.x;
  int i = blockIdx.x * SCAN_B + t;
  int v = (i < n) ? cnt[i] : 0;
  sm[t] = v;
  if (t < 64) {
    int a = 0;
    for (int j = t; j < blockIdx.x; j += 64) a += bsum[j];
#pragma unroll
    for (int o = 32; o; o >>= 1) a += __shfl_down(a, o);
    if (t == 0) boff_s = a;
  }
  __syncthreads();
  for (int off = 1; off < SCAN_B; off <<= 1) {
    int tv = (t >= off) ? sm[t - off] : 0;
    __syncthreads();
    sm[t] += tv;
    __syncthreads();
  }
  int incl = sm[t] + boff_s;
  if (i < n) {
    int start = incl - v;
    rowp[i] = start;
    cursor[i] = start;
    dinv[i] = rsqrtf((float)(v + 1));
    if (i == n - 1) rowp[n] = incl;
  }
}

__global__ void k_fill(const int* __restrict__ src, const int* __restrict__ dst,
                       int* __restrict__ cursor, int* __restrict__ ssrc, int e) {
  int i = blockIdx.x * blockDim.x + threadIdx.x;
  if (i < e) {
    int d = dst[i];
    int pos = atomicAdd(&cursor[d], 1);
    ssrc[pos] = src[i];
  }
}

// transpose+convert both weights in one launch
__global__ void k_tw2(const float* __restrict__ W1, short* __restrict__ w1t,
                      const float* __restrict__ W2, short* __restrict__ w2t) {
  int idx = blockIdx.x * blockDim.x + threadIdx.x;
  const int sz1 = IN_F * HID;
  if (idx < sz1) {
    int nn = idx / IN_F, kk = idx - nn * IN_F;
    w1t[idx] = f2bf(W1[kk * HID + nn]);
  } else {
    int j = idx - sz1;
    if (j < HID * OUTF) {
      int nn = j / HID, kk = j - nn * HID;
      w2t[j] = f2bf(W2[kk * OUTF + nn]);
    }
  }
}

// ---------------- GEMM1: C[M,256](bf16) = A[M,K](f32) @ Bt[256,K]^T -------
// 64x256 tile, BK=32, 256 thr (4 waves, wave n-offset 64), register-prefetch,
// f32->bf16 cvt fused into staging. 782 blocks for better HBM overlap.
__global__ __launch_bounds__(256, 2) void k_gemm1(const float* __restrict__ A,
                                                  const short* __restrict__ Bt,
                                                  short* __restrict__ C,
                                                  int M, int K) {
  __shared__ __align__(16) short As[64 * 32];
  __shared__ __align__(16) short Bs[256 * 32];
  const int tid = threadIdx.x;
  const int tile_m = blockIdx.x * 64;
  const int wave = tid >> 6;
  const int lane = tid & 63;
  const int wn = wave * 64;
  const int lrow = lane & 15;
  const int quad = lane >> 4;

  // A: 256 chunks of 8 f32; thread -> chunk tid (row=tid>>2, col=(tid&3)*8)
  const int rA = tid >> 2;
  const int colA = (tid & 3) * 8;
  int gr = tile_m + rA; if (gr >= M) gr = M - 1;
  const float* pA = A + (size_t)gr * K + colA;
  const short* pB = Bt + (size_t)rA * K + colA;  // + q*64 rows

  float4 a0, a1;
  bf16x8 bgl[4];
  auto ldglb = [&](int k0) {
    a0 = *(const float4*)(pA + k0);
    a1 = *(const float4*)(pA + k0 + 4);
#pragma unroll
    for (int q = 0; q < 4; q++)
      bgl[q] = *(const bf16x8*)(pB + (size_t)(q * 64) * K + k0);
  };

  f32x4 zero = {0.f, 0.f, 0.f, 0.f};
  f32x4 acc[4][4];
#pragma unroll
  for (int i = 0; i < 4; i++)
#pragma unroll
    for (int j = 0; j < 4; j++) acc[i][j] = zero;

  ldglb(0);
  for (int k0 = 0; k0 < K; k0 += 32) {
    bf16x8 pk;
    pk[0] = f2bf(a0.x); pk[1] = f2bf(a0.y); pk[2] = f2bf(a0.z); pk[3] = f2bf(a0.w);
    pk[4] = f2bf(a1.x); pk[5] = f2bf(a1.y); pk[6] = f2bf(a1.z); pk[7] = f2bf(a1.w);
    *(bf16x8*)&As[tid * 8] = pk;
#pragma unroll
    for (int q = 0; q < 4; q++) *(bf16x8*)&Bs[(tid + q * 256) * 8] = bgl[q];
    __syncthreads();

    if (k0 + 32 < K) ldglb(k0 + 32);  // next tile in flight across MFMA

    bf16x8 af[4], bfr[4];
#pragma unroll
    for (int i = 0; i < 4; i++)
      af[i] = *(const bf16x8*)&As[(i * 16 + lrow) * 32 + quad * 8];
#pragma unroll
    for (int j = 0; j < 4; j++)
      bfr[j] = *(const bf16x8*)&Bs[(wn + j * 16 + lrow) * 32 + quad * 8];
#pragma unroll
    for (int i = 0; i < 4; i++)
#pragma unroll
      for (int j = 0; j < 4; j++)
        acc[i][j] = __builtin_amdgcn_mfma_f32_16x16x32_bf16(af[i], bfr[j],
                                                            acc[i][j], 0, 0, 0);
    __syncthreads();
  }

#pragma unroll
  for (int i = 0; i < 4; i++) {
#pragma unroll
    for (int r = 0; r < 4; r++) {
      int grow = tile_m + i * 16 + quad * 4 + r;
      if (grow < M) {
#pragma unroll
        for (int j = 0; j < 4; j++) {
          int gcol = wn + j * 16 + lrow;
          C[(size_t)grow * HID + gcol] = f2bf(acc[i][j][r]);
        }
      }
    }
  }
}

// ---------------- async MFMA GEMM (m97 structure), bf16 A (GEMM2) ---------
__device__ inline void glds16(const short* g, short* l) {
  __builtin_amdgcn_global_load_lds((const __attribute__((address_space(1))) void*)g,
                                   (__attribute__((address_space(3))) void*)l, 16, 0, 0);
}

__global__ __launch_bounds__(256) void k_gemm_a(const short* __restrict__ A,
                                                const short* __restrict__ Bt,
                                                short* __restrict__ C,
                                                int M, int N, int K) {
  __shared__ __align__(16) short As[128 * 32];
  __shared__ __align__(16) short Bs[128 * 32];
  const int tid = threadIdx.x;
  const int tile_m = blockIdx.x * 128;
  const int tile_n = blockIdx.y * 128;
  const int wave = tid >> 6;
  const int lane = tid & 63;
  const int wm = (wave & 1) * 64;
  const int wn = (wave >> 1) * 64;
  const int lrow = lane & 15;
  const int quad = lane >> 4;

  const int c = tid, c2 = tid + 256;
  const int rowA = c >> 2, colA = (c & 3) * 8;
  const int rowA2 = c2 >> 2, colA2 = (c2 & 3) * 8;
  int grA = tile_m + rowA;  if (grA >= M) grA = M - 1;
  int grA2 = tile_m + rowA2; if (grA2 >= M) grA2 = M - 1;
  const short* pA = A + (size_t)grA * K + colA;
  const short* pA2 = A + (size_t)grA2 * K + colA2;
  const short* pB = Bt + (size_t)(tile_n + rowA) * K + colA;
  const short* pB2 = Bt + (size_t)(tile_n + rowA2) * K + colA2;

  f32x4 zero = {0.f, 0.f, 0.f, 0.f};
  f32x4 acc[4][4];
#pragma unroll
  for (int i = 0; i < 4; i++)
#pragma unroll
    for (int j = 0; j < 4; j++) acc[i][j] = zero;

  for (int k0 = 0; k0 < K; k0 += 32) {
    glds16(pA + k0, &As[c * 8]);
    glds16(pA2 + k0, &As[c2 * 8]);
    glds16(pB + k0, &Bs[c * 8]);
    glds16(pB2 + k0, &Bs[c2 * 8]);
    __builtin_amdgcn_s_waitcnt(0xcf70);  // vmcnt(0)
    __syncthreads();

    bf16x8 af[4], bfr[4];
#pragma unroll
    for (int i = 0; i < 4; i++)
      af[i] = *(const bf16x8*)&As[(wm + i * 16 + lrow) * 32 + quad * 8];
#pragma unroll
    for (int j = 0; j < 4; j++)
      bfr[j] = *(const bf16x8*)&Bs[(wn + j * 16 + lrow) * 32 + quad * 8];
#pragma unroll
    for (int i = 0; i < 4; i++)
#pragma unroll
      for (int j = 0; j < 4; j++)
        acc[i][j] = __builtin_amdgcn_mfma_f32_16x16x32_bf16(af[i], bfr[j],
                                                            acc[i][j], 0, 0, 0);
    __syncthreads();
  }

#pragma unroll
  for (int i = 0; i < 4; i++) {
#pragma unroll
    for (int r = 0; r < 4; r++) {
      int grow = tile_m + wm + i * 16 + quad * 4 + r;
      if (grow < M) {
#pragma unroll
        for (int j = 0; j < 4; j++) {
          int gcol = tile_n + wn + j * 16 + lrow;
          C[(size_t)grow * N + gcol] = f2bf(acc[i][j][r]);
        }
      }
    }
  }
}

// ---------------- CSR aggregation: group-split wave, 16B/lane gathers -----
// Wave = G groups; each group gathers one full row per step (bf16x8/lane).
// G=2 for F=256, G=4 for F=128. Fold across groups via shfl_xor at end.
// out[i,:] = bias + di*( di*H[i,:] + sum_e dinv[src]*H[src,:] ), opt ReLU.
template <int F, bool RELU, typename OT>
__global__ __launch_bounds__(256) void k_agg3(const short* __restrict__ H,
                                              const int* __restrict__ rowp,
                                              const int* __restrict__ ssrc,
                                              const float* __restrict__ dinv,
                                              const float* __restrict__ bias,
                                              OT* __restrict__ out, int n) {
  constexpr int G = (F == 256) ? 2 : 4;      // groups per wave
  constexpr int GL = 64 / G;                 // lanes per group (row = GL*8 feats)
  static_assert(GL * 8 == F, "row width mismatch");
  const int lane = threadIdx.x & 63;
  const int i = blockIdx.x * 4 + (threadIdx.x >> 6);
  if (i >= n) return;
  const int grp = lane / GL;
  const int sub = lane % GL;
  const int fo = sub * 8;                    // feature offset of this lane
  const float di = dinv[i];

  float acc[8];
#pragma unroll
  for (int e2 = 0; e2 < 8; e2++) acc[e2] = 0.f;

  // self term (group 0 only)
  if (grp == 0) {
    bf16x8 v = *(const bf16x8*)(H + (size_t)i * F + fo);
#pragma unroll
    for (int e2 = 0; e2 < 8; e2++) acc[e2] = di * bf2f((uint16_t)v[e2]);
  }

  const int e1 = rowp[i + 1];
  int p = rowp[i];
  for (; p < e1; p += 2 * G) {
#pragma unroll
    for (int u = 0; u < 2; ++u) {
      int idx = p + u * G + grp;
      bool ok = idx < e1;
      int s = ok ? ssrc[idx] : i;
      float ds = ok ? dinv[s] : 0.f;
      bf16x8 v = *(const bf16x8*)(H + (size_t)s * F + fo);
#pragma unroll
      for (int e2 = 0; e2 < 8; e2++) acc[e2] += ds * bf2f((uint16_t)v[e2]);
    }
  }

  // fold groups
#pragma unroll
  for (int e2 = 0; e2 < 8; e2++) {
    if (G == 4) acc[e2] += __shfl_xor(acc[e2], 16);
    acc[e2] += __shfl_xor(acc[e2], 32);
  }

  if (grp == 0) {
    float o[8];
#pragma unroll
    for (int e2 = 0; e2 < 8; e2++) {
      o[e2] = di * acc[e2] + bias[fo + e2];
      if (RELU) o[e2] = fmaxf(o[e2], 0.f);
    }
    if constexpr (sizeof(OT) == 2) {
      bf16x8 pk;
#pragma unroll
      for (int e2 = 0; e2 < 8; e2++) pk[e2] = f2bf(o[e2]);
      *(bf16x8*)((short*)out + (size_t)i * F + fo) = pk;
    } else {
      float* po = (float*)out + (size_t)i * F + fo;
      *(float4*)po = make_float4(o[0], o[1], o[2], o[3]);
      *(float4*)(po + 4) = make_float4(o[4], o[5], o[6], o[7]);
    }
  }
}

// ---------------- launch ----------------
extern "C" void kernel_launch(void* const* d_in, const int* in_sizes, int n_in,
                              void* d_out, int out_size, void* d_ws, size_t ws_size,
                              hipStream_t stream) {
  const float* x = (const float*)d_in[0];
  const int* ei = (const int*)d_in[1];
  const float* W1 = (const float*)d_in[2];
  const float* b1 = (const float*)d_in[3];
  const float* W2 = (const float*)d_in[4];
  const float* b2 = (const float*)d_in[5];
  float* out = (float*)d_out;

  const int n = in_sizes[0] / IN_F;   // 50000
  const int e = in_sizes[1] / 2;      // 800000
  const int* e_src = ei;
  const int* e_dst = ei + e;
  const int nb = (n + SCAN_B - 1) / SCAN_B;

  uint8_t* ws = (uint8_t*)d_ws;
  size_t off = 0;
  auto carve = [&](size_t bytes) {
    uint8_t* p = ws + off;
    off = (off + bytes + 255) & ~(size_t)255;
    return p;
  };
  short* h1 = (short*)carve((size_t)n * HID * 2);
  short* h2 = (short*)carve((size_t)n * HID * 2);
  short* t2 = (short*)carve((size_t)n * OUTF * 2);
  short* w1t = (short*)carve((size_t)HID * IN_F * 2);
  short* w2t = (short*)carve((size_t)OUTF * HID * 2);
  int* cnt = (int*)carve((size_t)n * 4);
  int* rowp = (int*)carve((size_t)(n + 1) * 4);
  int* cursor = (int*)carve((size_t)n * 4);
  float* dinv = (float*)carve((size_t)n * 4);
  int* ssrc = (int*)carve((size_t)e * 4);
  int* bsum = (int*)carve((size_t)nb * 4);
  (void)n_in; (void)out_size; (void)ws_size;

  // CSR build (5 launches)
  k_zero<<<(n + 255) / 256, 256, 0, stream>>>(cnt, n);
  k_hist<<<(e + 255) / 256, 256, 0, stream>>>(e_dst, cnt, e);
  k_bsum<<<nb, SCAN_B, 0, stream>>>(cnt, bsum, n);
  k_scan2<<<nb, SCAN_B, 0, stream>>>(cnt, bsum, rowp, cursor, dinv, n);
  k_fill<<<(e + 255) / 256, 256, 0, stream>>>(e_src, e_dst, cursor, ssrc, e);

  // weights (1 launch)
  k_tw2<<<(IN_F * HID + HID * OUTF + 255) / 256, 256, 0, stream>>>(W1, w1t, W2, w2t);

  // layer 1: h1 = x @ W1 (f32 A read once); h2 = relu(agg(h1)+b1)
  k_gemm1<<<(n + 63) / 64, 256, 0, stream>>>(x, w1t, h1, n, IN_F);
  k_agg3<HID, true, short><<<(n + 3) / 4, 256, 0, stream>>>(h1, rowp, ssrc, dinv, b1, h2, n);

  // layer 2: t2 = h2 @ W2 ; out = agg(t2) + b2
  {
    dim3 grid((n + 127) / 128, OUTF / 128);
    k_gemm_a<<<grid, 256, 0, stream>>>(h2, w2t, t2, n, OUTF, HID);
  }
  k_agg3<OUTF, false, float><<<(n + 3) / 4, 256, 0, stream>>>(t2, rowp, ssrc, dinv, b2, out, n);
}

// Round 5
// 467.984 us; speedup vs baseline: 1.0086x; 1.0086x over previous
//
#include <hip/hip_runtime.h>
#include <stdint.h>

#define IN_F 768
#define HID 256
#define OUTF 128

typedef short bf16x8 __attribute__((ext_vector_type(8)));
typedef float f32x4 __attribute__((ext_vector_type(4)));

__device__ inline short f2bf(float f) {
  union { float f; uint32_t u; } x; x.f = f;
  uint32_t r = (x.u + 0x7fffu + ((x.u >> 16) & 1u)) >> 16;  // RNE, finite inputs
  return (short)(uint16_t)r;
}
__device__ inline float bf2f(uint32_t bits) {
  union { uint32_t u; float f; } x; x.u = bits << 16; return x.f;
}

__device__ inline void glds16(const short* g, short* l) {
  __builtin_amdgcn_global_load_lds((const __attribute__((address_space(1))) void*)g,
                                   (__attribute__((address_space(3))) void*)l, 16, 0, 0);
}

// ---------------- CSR build ----------------
__global__ void k_zero(int* p, int n) {
  int i = blockIdx.x * blockDim.x + threadIdx.x;
  if (i < n) p[i] = 0;
}

__global__ void k_hist(const int* __restrict__ dst, int* __restrict__ cnt, int e) {
  int i = blockIdx.x * blockDim.x + threadIdx.x;
  if (i < e) atomicAdd(&cnt[dst[i]], 1);
}

#define SCAN_B 1024
__global__ void k_bsum(const int* __restrict__ cnt, int* __restrict__ bsum, int n) {
  __shared__ int sm[SCAN_B];
  int t = threadIdx.x;
  int i = blockIdx.x * SCAN_B + t;
  sm[t] = (i < n) ? cnt[i] : 0;
  __syncthreads();
  for (int off = SCAN_B / 2; off > 0; off >>= 1) {
    if (t < off) sm[t] += sm[t + off];
    __syncthreads();
  }
  if (t == 0) bsum[blockIdx.x] = sm[0];
}

__global__ void k_scan2(const int* __restrict__ cnt, const int* __restrict__ bsum,
                        int* __restrict__ rowp, int* __restrict__ cursor,
                        float* __restrict__ dinv, int n) {
  __shared__ int sm[SCAN_B];
  __shared__ int boff_s;
  int t = threadIdx.x;
  int i = blockIdx.x * SCAN_B + t;
  int v = (i < n) ? cnt[i] : 0;
  sm[t] = v;
  if (t < 64) {
    int a = 0;
    for (int j = t; j < blockIdx.x; j += 64) a += bsum[j];
#pragma unroll
    for (int o = 32; o; o >>= 1) a += __shfl_down(a, o);
    if (t == 0) boff_s = a;
  }
  __syncthreads();
  for (int off = 1; off < SCAN_B; off <<= 1) {
    int tv = (t >= off) ? sm[t - off] : 0;
    __syncthreads();
    sm[t] += tv;
    __syncthreads();
  }
  int incl = sm[t] + boff_s;
  if (i < n) {
    int start = incl - v;
    rowp[i] = start;
    cursor[i] = start;
    dinv[i] = rsqrtf((float)(v + 1));
    if (i == n - 1) rowp[n] = incl;
  }
}

__global__ void k_fill(const int* __restrict__ src, const int* __restrict__ dst,
                       int* __restrict__ cursor, int* __restrict__ ssrc, int e) {
  int i = blockIdx.x * blockDim.x + threadIdx.x;
  if (i < e) {
    int d = dst[i];
    int pos = atomicAdd(&cursor[d], 1);
    ssrc[pos] = src[i];
  }
}

__global__ void k_tw2(const float* __restrict__ W1, short* __restrict__ w1t,
                      const float* __restrict__ W2, short* __restrict__ w2t) {
  int idx = blockIdx.x * blockDim.x + threadIdx.x;
  const int sz1 = IN_F * HID;
  if (idx < sz1) {
    int nn = idx / IN_F, kk = idx - nn * IN_F;
    w1t[idx] = f2bf(W1[kk * HID + nn]);
  } else {
    int j = idx - sz1;
    if (j < HID * OUTF) {
      int nn = j / HID, kk = j - nn * HID;
      w2t[j] = f2bf(W2[kk * OUTF + nn]);
    }
  }
}

// ---------------- GEMM1: C[M,256](bf16) = A[M,768](f32) @ Bt[256,768]^T ---
// 64x256 tile, BK=32, 24 iters. Double-buffered LDS, RAW barriers (no
// __syncthreads -> prefetch survives the barrier). B via global_load_lds,
// A via register prefetch + fused f32->bf16 cvt + one ds_write_b128.
__global__ __launch_bounds__(256) void k_gemm1p(const float* __restrict__ A,
                                                const short* __restrict__ Bt,
                                                short* __restrict__ C, int M) {
  __shared__ __align__(16) short As[2][64 * 32];    // 4 KB / buf
  __shared__ __align__(16) short Bs[2][256 * 32];   // 16 KB / buf
  const int tid = threadIdx.x;
  const int tile_m = blockIdx.x * 64;
  const int wave = tid >> 6;
  const int lane = tid & 63;
  const int wn = wave * 64;
  const int lrow = lane & 15;
  const int quad = lane >> 4;

  // B glds: 16 chunks of 1KB; wave w owns chunks w*4 + c (c=0..3).
  // chunk holds 16 rows x 32 bf16; lane l -> row chunk*16 + (l>>2), col (l&3)*8.
  const int bchunk0 = wave * 4;
  const short* pBl = Bt + (size_t)(bchunk0 * 16 + (lane >> 2)) * IN_F + (lane & 3) * 8;
  // A regs: thread t -> row tile_m + (t>>2), col (t&3)*8 (8 f32).
  int ar = tile_m + (tid >> 2);
  if (ar >= M) ar = M - 1;
  const float* pAl = A + (size_t)ar * IN_F + (tid & 3) * 8;

  f32x4 zero = {0.f, 0.f, 0.f, 0.f};
  f32x4 acc[4][4];
#pragma unroll
  for (int i = 0; i < 4; i++)
#pragma unroll
    for (int j = 0; j < 4; j++) acc[i][j] = zero;

  // prologue: tile 0 in flight (B first, then A — vmcnt FIFO invariant)
#pragma unroll
  for (int c = 0; c < 4; c++)
    glds16(pBl + (size_t)c * 16 * IN_F, &Bs[0][(bchunk0 + c) * 512]);
  float4 a1lo = *(const float4*)(pAl);
  float4 a1hi = *(const float4*)(pAl + 4);

  const int NIT = IN_F / 32;  // 24
  for (int it = 0; it < NIT; ++it) {
    const int b = it & 1;
    if (it + 1 < NIT) {
      const int k1 = (it + 1) * 32;
#pragma unroll
      for (int c = 0; c < 4; c++)
        glds16(pBl + (size_t)c * 16 * IN_F + k1, &Bs[b ^ 1][(bchunk0 + c) * 512]);
    }
    float4 a2lo, a2hi;
    if (it + 1 < NIT) {
      a2lo = *(const float4*)(pAl + (it + 1) * 32);
      a2hi = *(const float4*)(pAl + (it + 1) * 32 + 4);
    }
    // stage A(it): cvt + single ds_write_b128 (compiler waits its own vmcnt dep)
    bf16x8 pk;
    pk[0] = f2bf(a1lo.x); pk[1] = f2bf(a1lo.y); pk[2] = f2bf(a1lo.z); pk[3] = f2bf(a1lo.w);
    pk[4] = f2bf(a1hi.x); pk[5] = f2bf(a1hi.y); pk[6] = f2bf(a1hi.z); pk[7] = f2bf(a1hi.w);
    *(bf16x8*)&As[b][tid * 8] = pk;
    a1lo = a2lo; a1hi = a2hi;

    // top barrier: drain LDS writes + enough vm to retire tile-it's B glds
    // (<=8 newer vm ops possible: A(it) 2 + B(it+1) 4 + A(it+1) 2 minus retired)
    if (it + 1 < NIT)
      __builtin_amdgcn_s_waitcnt(0x0078);  // vmcnt(8) lgkmcnt(0)
    else
      __builtin_amdgcn_s_waitcnt(0x0072);  // vmcnt(2) lgkmcnt(0)
    __builtin_amdgcn_s_barrier();

    bf16x8 af[4], bfr[4];
#pragma unroll
    for (int i = 0; i < 4; i++)
      af[i] = *(const bf16x8*)&As[b][(i * 16 + lrow) * 32 + quad * 8];
#pragma unroll
    for (int j = 0; j < 4; j++)
      bfr[j] = *(const bf16x8*)&Bs[b][(wn + j * 16 + lrow) * 32 + quad * 8];
#pragma unroll
    for (int i = 0; i < 4; i++)
#pragma unroll
      for (int j = 0; j < 4; j++)
        acc[i][j] = __builtin_amdgcn_mfma_f32_16x16x32_bf16(af[i], bfr[j],
                                                            acc[i][j], 0, 0, 0);
    // bottom barrier: RAW — ds_reads already consumed by MFMA (compiler lgkm),
    // next-tile glds/loads stay in flight across it.
    __builtin_amdgcn_s_barrier();
  }

#pragma unroll
  for (int i = 0; i < 4; i++) {
#pragma unroll
    for (int r = 0; r < 4; r++) {
      int grow = tile_m + i * 16 + quad * 4 + r;
      if (grow < M) {
#pragma unroll
        for (int j = 0; j < 4; j++)
          C[(size_t)grow * HID + wn + j * 16 + lrow] = f2bf(acc[i][j][r]);
      }
    }
  }
}

// ---------------- GEMM2: C[M,128](bf16) = A[M,256](bf16) @ Bt[128,256]^T --
// 128x128 tile, BK=32, 8 iters, pure-glds double buffer, raw barriers.
__global__ __launch_bounds__(256) void k_gemm2p(const short* __restrict__ A,
                                                const short* __restrict__ Bt,
                                                short* __restrict__ C, int M) {
  __shared__ __align__(16) short As[2][128 * 32];   // 8 KB / buf
  __shared__ __align__(16) short Bs[2][128 * 32];
  const int tid = threadIdx.x;
  const int tile_m = blockIdx.x * 128;
  const int wave = tid >> 6;
  const int lane = tid & 63;
  const int wm = (wave & 1) * 64;
  const int wn = (wave >> 1) * 64;
  const int lrow = lane & 15;
  const int quad = lane >> 4;

  // 8 chunks of 1KB per tile; wave w owns chunks w*2 + c (c=0,1).
  const int chunk0 = wave * 2;
  const int rl = (lane >> 2);      // row within chunk
  const int cl = (lane & 3) * 8;   // col
  int garow0 = tile_m + chunk0 * 16 + rl;      if (garow0 >= M) garow0 = M - 1;
  int garow1 = tile_m + (chunk0 + 1) * 16 + rl; if (garow1 >= M) garow1 = M - 1;
  const short* pA0 = A + (size_t)garow0 * HID + cl;
  const short* pA1 = A + (size_t)garow1 * HID + cl;
  const short* pB0 = Bt + (size_t)(chunk0 * 16 + rl) * HID + cl;
  const short* pB1 = Bt + (size_t)((chunk0 + 1) * 16 + rl) * HID + cl;

  f32x4 zero = {0.f, 0.f, 0.f, 0.f};
  f32x4 acc[4][4];
#pragma unroll
  for (int i = 0; i < 4; i++)
#pragma unroll
    for (int j = 0; j < 4; j++) acc[i][j] = zero;

  auto issue = [&](int k0, int b) {
    glds16(pA0 + k0, &As[b][chunk0 * 512]);
    glds16(pA1 + k0, &As[b][(chunk0 + 1) * 512]);
    glds16(pB0 + k0, &Bs[b][chunk0 * 512]);
    glds16(pB1 + k0, &Bs[b][(chunk0 + 1) * 512]);
  };

  issue(0, 0);
  const int NIT = HID / 32;  // 8
  for (int it = 0; it < NIT; ++it) {
    const int b = it & 1;
    if (it + 1 < NIT) {
      issue((it + 1) * 32, b ^ 1);
      __builtin_amdgcn_s_waitcnt(0x0F74);  // vmcnt(4): tile-it resident
    } else {
      __builtin_amdgcn_s_waitcnt(0x0F70);  // vmcnt(0)
    }
    __builtin_amdgcn_s_barrier();

    bf16x8 af[4], bfr[4];
#pragma unroll
    for (int i = 0; i < 4; i++)
      af[i] = *(const bf16x8*)&As[b][(wm + i * 16 + lrow) * 32 + quad * 8];
#pragma unroll
    for (int j = 0; j < 4; j++)
      bfr[j] = *(const bf16x8*)&Bs[b][(wn + j * 16 + lrow) * 32 + quad * 8];
#pragma unroll
    for (int i = 0; i < 4; i++)
#pragma unroll
      for (int j = 0; j < 4; j++)
        acc[i][j] = __builtin_amdgcn_mfma_f32_16x16x32_bf16(af[i], bfr[j],
                                                            acc[i][j], 0, 0, 0);
    __builtin_amdgcn_s_barrier();
  }

#pragma unroll
  for (int i = 0; i < 4; i++) {
#pragma unroll
    for (int r = 0; r < 4; r++) {
      int grow = tile_m + wm + i * 16 + quad * 4 + r;
      if (grow < M) {
#pragma unroll
        for (int j = 0; j < 4; j++)
          C[(size_t)grow * OUTF + wn + j * 16 + lrow] = f2bf(acc[i][j][r]);
      }
    }
  }
}

// ---------------- CSR aggregation: group-split wave, 16B/lane gathers -----
template <int F, bool RELU, typename OT>
__global__ __launch_bounds__(256) void k_agg3(const short* __restrict__ H,
                                              const int* __restrict__ rowp,
                                              const int* __restrict__ ssrc,
                                              const float* __restrict__ dinv,
                                              const float* __restrict__ bias,
                                              OT* __restrict__ out, int n) {
  constexpr int G = (F == 256) ? 2 : 4;
  constexpr int GL = 64 / G;
  static_assert(GL * 8 == F, "row width mismatch");
  const int lane = threadIdx.x & 63;
  const int i = blockIdx.x * 4 + (threadIdx.x >> 6);
  if (i >= n) return;
  const int grp = lane / GL;
  const int sub = lane % GL;
  const int fo = sub * 8;
  const float di = dinv[i];

  float acc[8];
#pragma unroll
  for (int e2 = 0; e2 < 8; e2++) acc[e2] = 0.f;

  if (grp == 0) {
    bf16x8 v = *(const bf16x8*)(H + (size_t)i * F + fo);
#pragma unroll
    for (int e2 = 0; e2 < 8; e2++) acc[e2] = di * bf2f((uint16_t)v[e2]);
  }

  const int e1 = rowp[i + 1];
  int p = rowp[i];
  for (; p < e1; p += 2 * G) {
#pragma unroll
    for (int u = 0; u < 2; ++u) {
      int idx = p + u * G + grp;
      bool ok = idx < e1;
      int s = ok ? ssrc[idx] : i;
      float ds = ok ? dinv[s] : 0.f;
      bf16x8 v = *(const bf16x8*)(H + (size_t)s * F + fo);
#pragma unroll
      for (int e2 = 0; e2 < 8; e2++) acc[e2] += ds * bf2f((uint16_t)v[e2]);
    }
  }

#pragma unroll
  for (int e2 = 0; e2 < 8; e2++) {
    if (G == 4) acc[e2] += __shfl_xor(acc[e2], 16);
    acc[e2] += __shfl_xor(acc[e2], 32);
  }

  if (grp == 0) {
    float o[8];
#pragma unroll
    for (int e2 = 0; e2 < 8; e2++) {
      o[e2] = di * acc[e2] + bias[fo + e2];
      if (RELU) o[e2] = fmaxf(o[e2], 0.f);
    }
    if constexpr (sizeof(OT) == 2) {
      bf16x8 pk;
#pragma unroll
      for (int e2 = 0; e2 < 8; e2++) pk[e2] = f2bf(o[e2]);
      *(bf16x8*)((short*)out + (size_t)i * F + fo) = pk;
    } else {
      float* po = (float*)out + (size_t)i * F + fo;
      *(float4*)po = make_float4(o[0], o[1], o[2], o[3]);
      *(float4*)(po + 4) = make_float4(o[4], o[5], o[6], o[7]);
    }
  }
}

// ---------------- launch ----------------
extern "C" void kernel_launch(void* const* d_in, const int* in_sizes, int n_in,
                              void* d_out, int out_size, void* d_ws, size_t ws_size,
                              hipStream_t stream) {
  const float* x = (const float*)d_in[0];
  const int* ei = (const int*)d_in[1];
  const float* W1 = (const float*)d_in[2];
  const float* b1 = (const float*)d_in[3];
  const float* W2 = (const float*)d_in[4];
  const float* b2 = (const float*)d_in[5];
  float* out = (float*)d_out;

  const int n = in_sizes[0] / IN_F;   // 50000
  const int e = in_sizes[1] / 2;      // 800000
  const int* e_src = ei;
  const int* e_dst = ei + e;
  const int nb = (n + SCAN_B - 1) / SCAN_B;

  uint8_t* ws = (uint8_t*)d_ws;
  size_t off = 0;
  auto carve = [&](size_t bytes) {
    uint8_t* p = ws + off;
    off = (off + bytes + 255) & ~(size_t)255;
    return p;
  };
  short* h1 = (short*)carve((size_t)n * HID * 2);
  short* h2 = (short*)carve((size_t)n * HID * 2);
  short* t2 = (short*)carve((size_t)n * OUTF * 2);
  short* w1t = (short*)carve((size_t)HID * IN_F * 2);
  short* w2t = (short*)carve((size_t)OUTF * HID * 2);
  int* cnt = (int*)carve((size_t)n * 4);
  int* rowp = (int*)carve((size_t)(n + 1) * 4);
  int* cursor = (int*)carve((size_t)n * 4);
  float* dinv = (float*)carve((size_t)n * 4);
  int* ssrc = (int*)carve((size_t)e * 4);
  int* bsum = (int*)carve((size_t)nb * 4);
  (void)n_in; (void)out_size; (void)ws_size;

  // CSR build
  k_zero<<<(n + 255) / 256, 256, 0, stream>>>(cnt, n);
  k_hist<<<(e + 255) / 256, 256, 0, stream>>>(e_dst, cnt, e);
  k_bsum<<<nb, SCAN_B, 0, stream>>>(cnt, bsum, n);
  k_scan2<<<nb, SCAN_B, 0, stream>>>(cnt, bsum, rowp, cursor, dinv, n);
  k_fill<<<(e + 255) / 256, 256, 0, stream>>>(e_src, e_dst, cursor, ssrc, e);

  // weights
  k_tw2<<<(IN_F * HID + HID * OUTF + 255) / 256, 256, 0, stream>>>(W1, w1t, W2, w2t);

  // layer 1: h1 = x @ W1 (pipelined, f32 A read once); h2 = relu(agg(h1)+b1)
  k_gemm1p<<<(n + 63) / 64, 256, 0, stream>>>(x, w1t, h1, n);
  k_agg3<HID, true, short><<<(n + 3) / 4, 256, 0, stream>>>(h1, rowp, ssrc, dinv, b1, h2, n);

  // layer 2: t2 = h2 @ W2 (pipelined); out = agg(t2) + b2
  k_gemm2p<<<(n + 127) / 128, 256, 0, stream>>>(h2, w2t, t2, n);
  k_agg3<OUTF, false, float><<<(n + 3) / 4, 256, 0, stream>>>(t2, rowp, ssrc, dinv, b2, out, n);
}